// Round 1
// baseline (345.578 us; speedup 1.0000x reference)
//
#include <hip/hip_runtime.h>

#define D     512
#define HW    (D * D)

// Bilinear sample of one image (base = &im[n,0,0,0], [3,HW]) at rescaled coords
// (rx, ry), accumulating mask-weighted result into r[3] and the clip penalty
// into *oob. Replicates reference: clip -> floor/ceil corners -> w = 1-|d|.
__device__ __forceinline__ void sample_acc(const float* __restrict__ im,
                                           float rx, float ry, float m,
                                           float r[3], double* oob) {
    float cxq = fminf(fmaxf(rx, 0.001f), 510.999f);
    float cyq = fminf(fmaxf(ry, 0.001f), 510.999f);
    float dx = rx - cxq;
    float dy = ry - cyq;
    // reference squares in f32 then means; double accumulation is strictly better
    *oob += (double)(dx * dx) + (double)(dy * dy);

    float xf = floorf(cxq), xc = ceilf(cxq);
    float yf = floorf(cyq), yc = ceilf(cyq);
    float wxf = 1.0f - (cxq - xf);
    float wxc = 1.0f - (xc - cxq);
    float wyf = 1.0f - (cyq - yf);
    float wyc = 1.0f - (yc - cyq);

    int ixf = (int)xf, ixc = (int)xc, iyf = (int)yf, iyc = (int)yc;
    int i00 = iyf + D * ixf;   // ind = y + D*x per reference
    int i10 = iyf + D * ixc;
    int i01 = iyc + D * ixf;
    int i11 = iyc + D * ixc;

    float w00 = wxf * wyf, w10 = wxc * wyf, w01 = wxf * wyc, w11 = wxc * wyc;

#pragma unroll
    for (int c = 0; c < 3; ++c) {
        const float* __restrict__ ch = im + (size_t)c * HW;
        float pix = w00 * ch[i00] + w10 * ch[i10] + w01 * ch[i01] + w11 * ch[i11];
        r[c] += m * pix;
    }
}

__global__ void __launch_bounds__(256) vm_kernel(
    const float* __restrict__ im1, const float* __restrict__ im2,
    const float* __restrict__ C,   const float* __restrict__ M1,
    const float* __restrict__ M2,  float* __restrict__ out,
    double* __restrict__ oob_ws)
{
    int idx = blockIdx.x * 256 + threadIdx.x;   // over N*HW
    int n = idx >> 18;          // / HW
    int p = idx & (HW - 1);     // % HW
    int i = p >> 9;             // row  (q0 = repeat)
    int j = p & (D - 1);        // col  (q1 = tile)

    float cx = C[(size_t)n * 2 * HW + p];
    float cy = C[(size_t)n * 2 * HW + HW + p];
    float m1 = M1[(size_t)n * HW + p];
    float m2 = M2[(size_t)n * HW + p];
    float tot = m1 + m2;
    float m1n = m1 / tot;
    float m2n = m2 / tot;

    float r[3] = {0.f, 0.f, 0.f};
    double oob = 0.0;

    const float* base1 = im1 + (size_t)n * 3 * HW;
    const float* base2 = im2 + (size_t)n * 3 * HW;

    // a: q + C, image1, mask M1n
    sample_acc(base1, ((float)i + cx) * (float)D, ((float)j + cy) * (float)D, m1n, r, &oob);
    // b: q - C, image2, mask M2n
    sample_acc(base2, ((float)i - cx) * (float)D, ((float)j - cy) * (float)D, m2n, r, &oob);

    size_t ob = (size_t)n * 3 * HW + p;
    out[ob]          = r[0];
    out[ob + HW]     = r[1];
    out[ob + 2 * HW] = r[2];

    // ---- block-level double reduction of oob -> one atomicAdd per block ----
    for (int off = 32; off > 0; off >>= 1)
        oob += __shfl_down(oob, off, 64);

    __shared__ double soob[4];
    int lane = threadIdx.x & 63;
    int w    = threadIdx.x >> 6;
    if (lane == 0) soob[w] = oob;
    __syncthreads();
    if (threadIdx.x == 0) {
        double s = soob[0] + soob[1] + soob[2] + soob[3];
        atomicAdd(oob_ws, s);
    }
}

__global__ void finalize_kernel(const double* __restrict__ oob_ws,
                                float* __restrict__ out_last, double inv_count)
{
    // loss = sum / (N*2*HW) / (D*D) * 1e-4   (a and b means share the count)
    double s = *oob_ws;
    *out_last = (float)(s * inv_count / (double)HW * 1e-4);
}

extern "C" void kernel_launch(void* const* d_in, const int* in_sizes, int n_in,
                              void* d_out, int out_size, void* d_ws, size_t ws_size,
                              hipStream_t stream) {
    const float* im1 = (const float*)d_in[0];
    const float* im2 = (const float*)d_in[1];
    const float* C   = (const float*)d_in[2];
    const float* M1  = (const float*)d_in[3];
    const float* M2  = (const float*)d_in[4];
    float* out = (float*)d_out;
    double* ws = (double*)d_ws;

    int N = in_sizes[3] / HW;            // M1 is [N,1,H,W]
    int total = N * HW;                  // threads
    int blocks = (total + 255) / 256;

    hipMemsetAsync(ws, 0, sizeof(double), stream);
    vm_kernel<<<blocks, 256, 0, stream>>>(im1, im2, C, M1, M2, out, ws);

    double inv_count = 1.0 / ((double)N * 2.0 * (double)HW);
    finalize_kernel<<<1, 1, 0, stream>>>(ws, out + (out_size - 1), inv_count);
}

// Round 2
// 219.261 us; speedup vs baseline: 1.5761x; 1.5761x over previous
//
#include <hip/hip_runtime.h>

#define D     512
#define HW    (D * D)
#define BLOCK 256
#define PPT   4                      // pixels per thread
#define PIX_PER_BLOCK (BLOCK * PPT)  // 1024

// Bilinear sample of one image (im = &image[n,0,0,0], layout [3,HW]) at
// rescaled coords (rx, ry); accumulate mask-weighted pixel into r[3] and the
// clip penalty into *oob. Mirrors reference semantics exactly (f32 math).
__device__ __forceinline__ void sample1(const float* __restrict__ im,
                                        float rx, float ry, float m,
                                        float r[3], double* oob) {
    float cxq = fminf(fmaxf(rx, 0.001f), 510.999f);
    float cyq = fminf(fmaxf(ry, 0.001f), 510.999f);
    float dx = rx - cxq;
    float dy = ry - cyq;
    *oob += (double)(dx * dx) + (double)(dy * dy);

    float xf = floorf(cxq), xc = ceilf(cxq);
    float yf = floorf(cyq), yc = ceilf(cyq);
    float wxf = 1.0f - (cxq - xf);
    float wxc = 1.0f - (xc - cxq);
    float wyf = 1.0f - (cyq - yf);
    float wyc = 1.0f - (yc - cyq);

    int ixf = (int)xf, ixc = (int)xc, iyf = (int)yf, iyc = (int)yc;
    int i00 = iyf + D * ixf;   // ind = y + D*x per reference
    int i10 = iyf + D * ixc;
    int i01 = iyc + D * ixf;
    int i11 = iyc + D * ixc;

    float w00 = wxf * wyf, w10 = wxc * wyf, w01 = wxf * wyc, w11 = wxc * wyc;

#pragma unroll
    for (int c = 0; c < 3; ++c) {
        const float* __restrict__ ch = im + (size_t)c * HW;
        float pix = w00 * ch[i00] + w10 * ch[i10] + w01 * ch[i01] + w11 * ch[i11];
        r[c] += m * pix;
    }
}

__global__ void __launch_bounds__(BLOCK) vm_kernel(
    const float* __restrict__ im1, const float* __restrict__ im2,
    const float* __restrict__ C,   const float* __restrict__ M1,
    const float* __restrict__ M2,  float* __restrict__ out,
    double* __restrict__ partials)
{
    int t   = blockIdx.x * BLOCK + threadIdx.x;
    int idx = t * PPT;            // first pixel index in [0, N*HW)
    int n = idx >> 18;            // / HW
    int p = idx & (HW - 1);       // % HW  (PPT pixels never cross n: HW%4==0)
    int i = p >> 9;               // row; 4 consecutive pixels share the row
    int j = p & (D - 1);          // col (multiple of 4, so j+3 <= 511)

    const size_t cb = (size_t)n * 2 * HW + p;
    const size_t mb = (size_t)n * HW + p;
    float4 cx4 = *(const float4*)(C  + cb);
    float4 cy4 = *(const float4*)(C  + cb + HW);
    float4 m14 = *(const float4*)(M1 + mb);
    float4 m24 = *(const float4*)(M2 + mb);

    float cx[PPT] = {cx4.x, cx4.y, cx4.z, cx4.w};
    float cy[PPT] = {cy4.x, cy4.y, cy4.z, cy4.w};
    float m1[PPT] = {m14.x, m14.y, m14.z, m14.w};
    float m2[PPT] = {m24.x, m24.y, m24.z, m24.w};

    const float* base1 = im1 + (size_t)n * 3 * HW;
    const float* base2 = im2 + (size_t)n * 3 * HW;

    float o0[PPT], o1[PPT], o2[PPT];
    double oob = 0.0;

#pragma unroll
    for (int k = 0; k < PPT; ++k) {
        float tot = m1[k] + m2[k];
        float m1n = m1[k] / tot;
        float m2n = m2[k] / tot;
        float r[3] = {0.f, 0.f, 0.f};
        float fi = (float)i;
        float fj = (float)(j + k);
        sample1(base1, (fi + cx[k]) * (float)D, (fj + cy[k]) * (float)D, m1n, r, &oob);
        sample1(base2, (fi - cx[k]) * (float)D, (fj - cy[k]) * (float)D, m2n, r, &oob);
        o0[k] = r[0]; o1[k] = r[1]; o2[k] = r[2];
    }

    size_t ob = (size_t)n * 3 * HW + p;
    *(float4*)(out + ob)          = make_float4(o0[0], o0[1], o0[2], o0[3]);
    *(float4*)(out + ob + HW)     = make_float4(o1[0], o1[1], o1[2], o1[3]);
    *(float4*)(out + ob + 2 * HW) = make_float4(o2[0], o2[1], o2[2], o2[3]);

    // ---- block reduction of oob -> ONE plain store per block (no atomics) ----
    for (int off = 32; off > 0; off >>= 1)
        oob += __shfl_down(oob, off, 64);

    __shared__ double soob[BLOCK / 64];
    int lane = threadIdx.x & 63;
    int w    = threadIdx.x >> 6;
    if (lane == 0) soob[w] = oob;
    __syncthreads();
    if (threadIdx.x == 0)
        partials[blockIdx.x] = soob[0] + soob[1] + soob[2] + soob[3];
}

__global__ void __launch_bounds__(BLOCK) reduce_kernel(
    const double* __restrict__ partials, int nparts,
    float* __restrict__ out_last, double scale)
{
    double s = 0.0;
    for (int i = threadIdx.x; i < nparts; i += BLOCK)
        s += partials[i];
    for (int off = 32; off > 0; off >>= 1)
        s += __shfl_down(s, off, 64);

    __shared__ double sm[BLOCK / 64];
    int lane = threadIdx.x & 63;
    int w    = threadIdx.x >> 6;
    if (lane == 0) sm[w] = s;
    __syncthreads();
    if (threadIdx.x == 0)
        *out_last = (float)((sm[0] + sm[1] + sm[2] + sm[3]) * scale);
}

extern "C" void kernel_launch(void* const* d_in, const int* in_sizes, int n_in,
                              void* d_out, int out_size, void* d_ws, size_t ws_size,
                              hipStream_t stream) {
    const float* im1 = (const float*)d_in[0];
    const float* im2 = (const float*)d_in[1];
    const float* C   = (const float*)d_in[2];
    const float* M1  = (const float*)d_in[3];
    const float* M2  = (const float*)d_in[4];
    float* out = (float*)d_out;
    double* ws = (double*)d_ws;

    int N = in_sizes[3] / HW;                 // M1 is [N,1,H,W]
    int total  = N * HW;
    int blocks = total / PIX_PER_BLOCK;       // 4096 for N=16

    vm_kernel<<<blocks, BLOCK, 0, stream>>>(im1, im2, C, M1, M2, out, ws);

    // loss = sum / (N*2*HW) / D^2 * 1e-4  (a and b share the mean count)
    double scale = 1.0 / ((double)N * 2.0 * (double)HW) / (double)HW * 1e-4;
    reduce_kernel<<<1, BLOCK, 0, stream>>>(ws, blocks, out + (out_size - 1), scale);
}

// Round 3
// 210.816 us; speedup vs baseline: 1.6392x; 1.0401x over previous
//
#include <hip/hip_runtime.h>

#define D     512
#define HW    (D * D)
#define BLOCK 256
#define ROWS  4          // rows per block tile
#define COLS  256        // cols per block tile (== BLOCK, 1 col per thread)

// Bilinear sample at rescaled coords (rx,ry). cpix[c*4+k] holds the high-high
// corner 2x2 pixel values (k: 00,10,01,11) for this image — block-uniform.
// For the ~98% of lanes where both coords clip high, the gather indices are
// exactly that corner, so we skip the per-lane gathers entirely.
__device__ __forceinline__ void sample1(const float* __restrict__ im,
                                        const float* __restrict__ cpix,
                                        float rx, float ry, float m,
                                        float r[3], float* oob) {
    float cxq = fminf(fmaxf(rx, 0.001f), 510.999f);
    float cyq = fminf(fmaxf(ry, 0.001f), 510.999f);
    float dx = rx - cxq;
    float dy = ry - cyq;
    *oob += dx * dx + dy * dy;

    float xf = floorf(cxq), xc = ceilf(cxq);
    float yf = floorf(cyq), yc = ceilf(cyq);
    float wxf = 1.0f - (cxq - xf);
    float wxc = 1.0f - (xc - cxq);
    float wyf = 1.0f - (cyq - yf);
    float wyc = 1.0f - (yc - cyq);
    float w00 = wxf * wyf, w10 = wxc * wyf, w01 = wxf * wyc, w11 = wxc * wyc;

    // default: block-uniform corner values (SGPR-resident, no VMEM)
    float p[3][4];
#pragma unroll
    for (int c = 0; c < 3; ++c) {
        p[c][0] = cpix[c * 4 + 0];
        p[c][1] = cpix[c * 4 + 1];
        p[c][2] = cpix[c * 4 + 2];
        p[c][3] = cpix[c * 4 + 3];
    }

    bool corner = (rx >= 510.999f) && (ry >= 510.999f);
    if (!corner) {
        // general path: per-lane gathers (divergent; whole wave skips via execz
        // when every lane is in the corner case)
        int ixf = (int)xf, ixc = (int)xc, iyf = (int)yf, iyc = (int)yc;
        int i00 = iyf + D * ixf;   // ind = y + D*x per reference
        int i10 = iyf + D * ixc;
        int i01 = iyc + D * ixf;
        int i11 = iyc + D * ixc;
#pragma unroll
        for (int c = 0; c < 3; ++c) {
            const float* __restrict__ ch = im + (size_t)c * HW;
            p[c][0] = ch[i00];
            p[c][1] = ch[i10];
            p[c][2] = ch[i01];
            p[c][3] = ch[i11];
        }
    }

#pragma unroll
    for (int c = 0; c < 3; ++c)
        r[c] += m * (w00 * p[c][0] + w10 * p[c][1] + w01 * p[c][2] + w11 * p[c][3]);
}

__global__ void __launch_bounds__(BLOCK) vm_kernel(
    const float* __restrict__ im1, const float* __restrict__ im2,
    const float* __restrict__ C,   const float* __restrict__ M1,
    const float* __restrict__ M2,  float* __restrict__ out,
    double* __restrict__ partials)
{
    // blockIdx.x = (n * 128 + row_group) * 2 + col_half
    int b    = blockIdx.x;
    int colh = b & 1;
    int rg   = (b >> 1) & 127;
    int n    = b >> 8;
    int j    = colh * COLS + threadIdx.x;    // this thread's column
    int i0   = rg * ROWS;                    // first row of the tile

    const float* base1 = im1 + (size_t)n * 3 * HW;
    const float* base2 = im2 + (size_t)n * 3 * HW;

    // High-high corner 2x2 values, block-uniform addresses -> scalar loads.
    // ind = y + D*x: p00=(510,510), p10=(x=511,y=510), p01=(x=510,y=511), p11
    float cp1[12], cp2[12];
#pragma unroll
    for (int c = 0; c < 3; ++c) {
        const float* c1 = base1 + (size_t)c * HW;
        const float* c2 = base2 + (size_t)c * HW;
        cp1[c * 4 + 0] = c1[510 + D * 510];
        cp1[c * 4 + 1] = c1[510 + D * 511];
        cp1[c * 4 + 2] = c1[511 + D * 510];
        cp1[c * 4 + 3] = c1[511 + D * 511];
        cp2[c * 4 + 0] = c2[510 + D * 510];
        cp2[c * 4 + 1] = c2[510 + D * 511];
        cp2[c * 4 + 2] = c2[511 + D * 510];
        cp2[c * 4 + 3] = c2[511 + D * 511];
    }

    const size_t cb = (size_t)n * 2 * HW;    // C base for this n
    const size_t mb = (size_t)n * HW;        // mask base
    const size_t ob = (size_t)n * 3 * HW;    // out base

    float oob = 0.0f;

#pragma unroll
    for (int r = 0; r < ROWS; ++r) {
        int i = i0 + r;
        size_t pp = (size_t)i * D + j;

        float cx = C[cb + pp];
        float cy = C[cb + HW + pp];
        float m1 = M1[mb + pp];
        float m2 = M2[mb + pp];
        float tot = m1 + m2;
        float m1n = m1 / tot;
        float m2n = m2 / tot;

        float acc[3] = {0.f, 0.f, 0.f};
        float fi = (float)i, fj = (float)j;
        sample1(base1, cp1, (fi + cx) * (float)D, (fj + cy) * (float)D, m1n, acc, &oob);
        sample1(base2, cp2, (fi - cx) * (float)D, (fj - cy) * (float)D, m2n, acc, &oob);

        out[ob + pp]          = acc[0];
        out[ob + HW + pp]     = acc[1];
        out[ob + 2 * HW + pp] = acc[2];
    }

    // ---- block reduction of oob (f32 within block; exact enough: partial
    // sums ~5e13 with rel err ~1e-7 vs loss scale) -> one double per block ----
    for (int off = 32; off > 0; off >>= 1)
        oob += __shfl_down(oob, off, 64);

    __shared__ float soob[BLOCK / 64];
    int lane = threadIdx.x & 63;
    int w    = threadIdx.x >> 6;
    if (lane == 0) soob[w] = oob;
    __syncthreads();
    if (threadIdx.x == 0)
        partials[blockIdx.x] = (double)soob[0] + (double)soob[1]
                             + (double)soob[2] + (double)soob[3];
}

__global__ void __launch_bounds__(BLOCK) reduce_kernel(
    const double* __restrict__ partials, int nparts,
    float* __restrict__ out_last, double scale)
{
    double s = 0.0;
    for (int i = threadIdx.x; i < nparts; i += BLOCK)
        s += partials[i];
    for (int off = 32; off > 0; off >>= 1)
        s += __shfl_down(s, off, 64);

    __shared__ double sm[BLOCK / 64];
    int lane = threadIdx.x & 63;
    int w    = threadIdx.x >> 6;
    if (lane == 0) sm[w] = s;
    __syncthreads();
    if (threadIdx.x == 0)
        *out_last = (float)((sm[0] + sm[1] + sm[2] + sm[3]) * scale);
}

extern "C" void kernel_launch(void* const* d_in, const int* in_sizes, int n_in,
                              void* d_out, int out_size, void* d_ws, size_t ws_size,
                              hipStream_t stream) {
    const float* im1 = (const float*)d_in[0];
    const float* im2 = (const float*)d_in[1];
    const float* C   = (const float*)d_in[2];
    const float* M1  = (const float*)d_in[3];
    const float* M2  = (const float*)d_in[4];
    float* out = (float*)d_out;
    double* ws = (double*)d_ws;

    int N = in_sizes[3] / HW;                        // M1 is [N,1,H,W]
    int blocks = N * (D / ROWS) * (D / COLS);        // 16*128*2 = 4096

    vm_kernel<<<blocks, BLOCK, 0, stream>>>(im1, im2, C, M1, M2, out, ws);

    // loss = sum / (N*2*HW) / D^2 * 1e-4  (a and b share the mean count)
    double scale = 1.0 / ((double)N * 2.0 * (double)HW) / (double)HW * 1e-4;
    reduce_kernel<<<1, BLOCK, 0, stream>>>(ws, blocks, out + (out_size - 1), scale);
}